// Round 2
// baseline (966.548 us; speedup 1.0000x reference)
//
#include <hip/hip_runtime.h>
#include <hip/hip_bf16.h>

// Problem constants (from reference setup_inputs)
constexpr int N_NODES = 50000;
constexpr int N_EDGES = 800000;
constexpr int E_TOT   = N_EDGES + N_NODES;   // with self loops
constexpr int F_IN    = 128;
constexpr int F_OUT   = 128;
constexpr int HEADS   = 2;
constexpr int WCOLS   = HEADS * F_OUT;       // 256

// ---------------------------------------------------------------------------
// Kernel 1: xw = x @ w   (x: [N,128], w: [128,256] -> xw: [N,256])
// w column held in registers (128 VGPR/thread); x row read via wave-uniform
// scalar loads. FMA-issue-bound.
// ---------------------------------------------------------------------------
constexpr int NODES_PER_BLOCK = 64;

__global__ __launch_bounds__(256) void proj_kernel(const float* __restrict__ x,
                                                   const float* __restrict__ w,
                                                   float* __restrict__ xw) {
    const int col = threadIdx.x;             // 0..255
    float wreg[F_IN];
#pragma unroll
    for (int k = 0; k < F_IN; ++k) wreg[k] = w[k * WCOLS + col];

    const int nstart = blockIdx.x * NODES_PER_BLOCK;
    const int nend   = min(nstart + NODES_PER_BLOCK, N_NODES);
    for (int n = nstart; n < nend; ++n) {
        const float4* xr = (const float4*)(x + (size_t)n * F_IN);  // uniform -> s_load
        float a0 = 0.f, a1 = 0.f, a2 = 0.f, a3 = 0.f;
#pragma unroll
        for (int kq = 0; kq < F_IN / 4; ++kq) {
            const float4 v = xr[kq];
            a0 = fmaf(v.x, wreg[4 * kq + 0], a0);
            a1 = fmaf(v.y, wreg[4 * kq + 1], a1);
            a2 = fmaf(v.z, wreg[4 * kq + 2], a2);
            a3 = fmaf(v.w, wreg[4 * kq + 3], a3);
        }
        xw[(size_t)n * WCOLS + col] = (a0 + a1) + (a2 + a3);
    }
}

// ---------------------------------------------------------------------------
// Kernel 2: s[n,h] = x[n,:] . u[:,h]   (per-node attention projection)
// One wave per node; lane handles features {2l, 2l+1}.
// ---------------------------------------------------------------------------
__global__ __launch_bounds__(256) void sproj_kernel(const float* __restrict__ x,
                                                    const float* __restrict__ u,
                                                    float2* __restrict__ s) {
    const int lane = threadIdx.x & 63;
    const int n    = blockIdx.x * 4 + (threadIdx.x >> 6);
    if (n >= N_NODES) return;
    const float2 xv = *(const float2*)(x + (size_t)n * F_IN + 2 * lane);
    const float4 uv = *(const float4*)(u + 4 * lane);   // u[2l][0..1], u[2l+1][0..1]
    float p0 = xv.x * uv.x + xv.y * uv.z;
    float p1 = xv.x * uv.y + xv.y * uv.w;
#pragma unroll
    for (int off = 1; off < 64; off <<= 1) {
        p0 += __shfl_xor(p0, off, 64);
        p1 += __shfl_xor(p1, off, 64);
    }
    if (lane == 0) s[n] = make_float2(p0, p1);
}

// ---------------------------------------------------------------------------
// Kernel 3: histogram of destinations (this is also the mean-divisor "cnt")
// ---------------------------------------------------------------------------
__global__ void hist_kernel(const int* __restrict__ ei, int* __restrict__ hist) {
    const int e = blockIdx.x * blockDim.x + threadIdx.x;
    if (e >= E_TOT) return;
    const int dst = (e < N_EDGES) ? ei[N_EDGES + e] : (e - N_EDGES);
    atomicAdd(&hist[dst], 1);
}

// ---------------------------------------------------------------------------
// Kernel 4: exclusive prefix sum of hist -> cursor  (single block, wave scan)
// ---------------------------------------------------------------------------
__global__ __launch_bounds__(1024) void scan_kernel(const int* __restrict__ hist,
                                                    int* __restrict__ cursor) {
    const int tid  = threadIdx.x;
    const int lane = tid & 63;
    const int wid  = tid >> 6;          // 0..15
    __shared__ int wsum[16];
    __shared__ int carry_s;
    if (tid == 0) carry_s = 0;
    __syncthreads();
    for (int base = 0; base < N_NODES; base += 1024) {
        const int i = base + tid;
        const int v = (i < N_NODES) ? hist[i] : 0;
        int xx = v;
#pragma unroll
        for (int off = 1; off < 64; off <<= 1) {
            const int t = __shfl_up(xx, off, 64);
            if (lane >= off) xx += t;
        }
        if (lane == 63) wsum[wid] = xx;
        __syncthreads();
        if (wid == 0) {
            int ws = (lane < 16) ? wsum[lane] : 0;
#pragma unroll
            for (int off = 1; off < 16; off <<= 1) {
                const int t = __shfl_up(ws, off, 64);
                if (lane >= off) ws += t;
            }
            if (lane < 16) wsum[lane] = ws;   // inclusive wave sums
        }
        __syncthreads();
        const int wave_excl = (wid == 0) ? 0 : wsum[wid - 1];
        const int carry     = carry_s;
        if (i < N_NODES) cursor[i] = carry + wave_excl + xx - v;  // exclusive
        __syncthreads();
        if (tid == 0) carry_s = carry + wsum[15];
        __syncthreads();
    }
}

// ---------------------------------------------------------------------------
// Kernel 5: attention + scatter into dst-sorted order.
// sorted[pos] = (q0, q1, bitcast(src), 0)
// ---------------------------------------------------------------------------
__global__ void scatter_kernel(const int* __restrict__ ei,
                               const float2* __restrict__ s,
                               const float* __restrict__ c,
                               int* __restrict__ cursor,
                               float4* __restrict__ sorted) {
    const int e = blockIdx.x * blockDim.x + threadIdx.x;
    if (e >= E_TOT) return;
    int src, dst;
    if (e < N_EDGES) { src = ei[e]; dst = ei[N_EDGES + e]; }
    else             { src = dst = e - N_EDGES; }
    const float2 ss = s[src];
    const float2 sd = s[dst];
    const float l0 = ss.x - sd.x + c[0];
    const float l1 = ss.y - sd.y + c[1];
    const float m  = fmaxf(l0, l1);
    const float e0 = __expf(l0 - m);
    const float e1 = __expf(l1 - m);
    const float inv = 1.0f / (e0 + e1);
    const int pos = atomicAdd(&cursor[dst], 1);
    sorted[pos] = make_float4(e0 * inv, e1 * inv, __int_as_float(src), 0.f);
}

// ---------------------------------------------------------------------------
// Kernel 6: per-node aggregation + mean + bias + relu + residual.
// One wave per node; lane handles features {2l, 2l+1}. No atomics.
// After scatter, cursor[n] == segment end; start = end - hist[n].
// ---------------------------------------------------------------------------
__global__ __launch_bounds__(256) void agg_kernel(const float* __restrict__ x,
                                                  const float* __restrict__ bias,
                                                  const float* __restrict__ xw,
                                                  const float4* __restrict__ sorted,
                                                  const int* __restrict__ hist,
                                                  const int* __restrict__ cursor,
                                                  float* __restrict__ out) {
    const int lane = threadIdx.x & 63;
    const int n    = blockIdx.x * 4 + (threadIdx.x >> 6);
    if (n >= N_NODES) return;
    const int deg   = hist[n];      // >=1 (self loop)
    const int end   = cursor[n];
    const int start = end - deg;
    float accx = 0.f, accy = 0.f;
    for (int i = start; i < end; ++i) {
        const float4 d = sorted[i];                     // wave-uniform -> scalar
        const int src  = __float_as_int(d.z);
        const float* p = xw + (size_t)src * WCOLS + 2 * lane;
        const float2 a = *(const float2*)p;             // head 0
        const float2 b = *(const float2*)(p + F_OUT);   // head 1
        accx = fmaf(d.x, a.x, fmaf(d.y, b.x, accx));
        accy = fmaf(d.x, a.y, fmaf(d.y, b.y, accy));
    }
    const float inv = 1.0f / (float)deg;
    const float2 bv = *(const float2*)(bias + 2 * lane);
    const float2 xv = *(const float2*)(x + (size_t)n * F_IN + 2 * lane);
    float2 r;
    r.x = xv.x + fmaxf(fmaf(accx, inv, bv.x), 0.f);
    r.y = xv.y + fmaxf(fmaf(accy, inv, bv.y), 0.f);
    *(float2*)(out + (size_t)n * F_OUT + 2 * lane) = r;
}

// ---------------------------------------------------------------------------
extern "C" void kernel_launch(void* const* d_in, const int* in_sizes, int n_in,
                              void* d_out, int out_size, void* d_ws, size_t ws_size,
                              hipStream_t stream) {
    const float* x    = (const float*)d_in[0];
    const int*   ei   = (const int*)  d_in[1];   // [2, N_EDGES] flat
    const float* u    = (const float*)d_in[2];
    const float* c    = (const float*)d_in[3];
    const float* w    = (const float*)d_in[4];
    const float* bias = (const float*)d_in[5];
    float* out = (float*)d_out;

    // workspace layout (16B-aligned segments):
    //   xw     [N*256 f32]   51,200,000 B
    //   s      [N   f32x2]      400,000 B
    //   hist   [N   i32]        200,000 B
    //   cursor [N   i32]        200,000 B
    //   sorted [E_TOT f32x4] 13,600,000 B
    char* p = (char*)d_ws;
    float*  xw     = (float*)p;              p += (size_t)N_NODES * WCOLS * sizeof(float);
    float2* s      = (float2*)p;             p += (size_t)N_NODES * sizeof(float2);
    int*    hist   = (int*)p;                p += (size_t)N_NODES * sizeof(int);
    int*    cursor = (int*)p;                p += (size_t)N_NODES * sizeof(int);
    float4* sorted = (float4*)p;

    hipMemsetAsync(hist, 0, (size_t)N_NODES * sizeof(int), stream);

    // 1) xw = x @ w
    proj_kernel<<<(N_NODES + NODES_PER_BLOCK - 1) / NODES_PER_BLOCK, 256, 0, stream>>>(x, w, xw);

    // 2) s = x @ u
    sproj_kernel<<<(N_NODES + 3) / 4, 256, 0, stream>>>(x, u, s);

    // 3) dst histogram (also the mean divisor)
    hist_kernel<<<(E_TOT + 255) / 256, 256, 0, stream>>>(ei, hist);

    // 4) exclusive scan -> cursor
    scan_kernel<<<1, 1024, 0, stream>>>(hist, cursor);

    // 5) attention + scatter into dst-sorted order
    scatter_kernel<<<(E_TOT + 255) / 256, 256, 0, stream>>>(ei, s, c, cursor, sorted);

    // 6) aggregate + finalize
    agg_kernel<<<(N_NODES + 3) / 4, 256, 0, stream>>>(x, bias, xw, sorted, hist, cursor, out);
}

// Round 3
// 410.078 us; speedup vs baseline: 2.3570x; 2.3570x over previous
//
#include <hip/hip_runtime.h>
#include <hip/hip_bf16.h>

// Problem constants (from reference setup_inputs)
constexpr int N_NODES = 50000;
constexpr int N_EDGES = 800000;
constexpr int E_TOT   = N_EDGES + N_NODES;   // with self loops
constexpr int F_IN    = 128;
constexpr int F_OUT   = 128;
constexpr int HEADS   = 2;
constexpr int WCOLS   = HEADS * F_OUT;       // 256

// ---------------------------------------------------------------------------
// Kernel 1: xw = x @ w   (x: [N,128], w: [128,256] -> xw: [N,256])
// thread = column; x rows via wave-uniform scalar loads (constant cache),
// w chunk (32 k-values for this column) in VGPRs, reused across 16 rows.
// 16 independent accumulator chains/thread -> FMA-issue-bound.
// ---------------------------------------------------------------------------
constexpr int ROWS_PER_BLOCK = 16;   // 50000 = 3125 * 16 exactly

__global__ __launch_bounds__(256, 4) void proj_kernel(const float* __restrict__ x,
                                                      const float* __restrict__ w,
                                                      float* __restrict__ xw) {
    const int col = threadIdx.x;                  // 0..255
    const int n0  = blockIdx.x * ROWS_PER_BLOCK;

    float acc[ROWS_PER_BLOCK];
#pragma unroll
    for (int r = 0; r < ROWS_PER_BLOCK; ++r) acc[r] = 0.f;

    for (int k0 = 0; k0 < F_IN; k0 += 32) {
        float wv[32];
#pragma unroll
        for (int i = 0; i < 32; ++i) wv[i] = w[(k0 + i) * WCOLS + col];
#pragma unroll
        for (int r = 0; r < ROWS_PER_BLOCK; ++r) {
            const float* xr = x + (size_t)(n0 + r) * F_IN + k0;   // uniform -> s_load
#pragma unroll
            for (int i = 0; i < 32; ++i) {
                acc[r] = fmaf(xr[i], wv[i], acc[r]);
            }
        }
    }
#pragma unroll
    for (int r = 0; r < ROWS_PER_BLOCK; ++r) {
        xw[(size_t)(n0 + r) * WCOLS + col] = acc[r];
    }
}

// ---------------------------------------------------------------------------
// Kernel 2: s[n,h] = x[n,:] . u[:,h]   (per-node attention projection)
// One wave per node; lane handles features {2l, 2l+1}.
// ---------------------------------------------------------------------------
__global__ __launch_bounds__(256) void sproj_kernel(const float* __restrict__ x,
                                                    const float* __restrict__ u,
                                                    float2* __restrict__ s) {
    const int lane = threadIdx.x & 63;
    const int n    = blockIdx.x * 4 + (threadIdx.x >> 6);
    if (n >= N_NODES) return;
    const float2 xv = *(const float2*)(x + (size_t)n * F_IN + 2 * lane);
    const float4 uv = *(const float4*)(u + 4 * lane);   // u[2l][0..1], u[2l+1][0..1]
    float p0 = xv.x * uv.x + xv.y * uv.z;
    float p1 = xv.x * uv.y + xv.y * uv.w;
#pragma unroll
    for (int off = 1; off < 64; off <<= 1) {
        p0 += __shfl_xor(p0, off, 64);
        p1 += __shfl_xor(p1, off, 64);
    }
    if (lane == 0) s[n] = make_float2(p0, p1);
}

// ---------------------------------------------------------------------------
// Kernel 3: histogram of destinations (this is also the mean-divisor "cnt")
// ---------------------------------------------------------------------------
__global__ void hist_kernel(const int* __restrict__ ei, int* __restrict__ hist) {
    const int e = blockIdx.x * blockDim.x + threadIdx.x;
    if (e >= E_TOT) return;
    const int dst = (e < N_EDGES) ? ei[N_EDGES + e] : (e - N_EDGES);
    atomicAdd(&hist[dst], 1);
}

// ---------------------------------------------------------------------------
// Kernel 4: exclusive prefix sum of hist -> cursor  (single block, wave scan)
// ---------------------------------------------------------------------------
__global__ __launch_bounds__(1024) void scan_kernel(const int* __restrict__ hist,
                                                    int* __restrict__ cursor) {
    const int tid  = threadIdx.x;
    const int lane = tid & 63;
    const int wid  = tid >> 6;          // 0..15
    __shared__ int wsum[16];
    __shared__ int carry_s;
    if (tid == 0) carry_s = 0;
    __syncthreads();
    for (int base = 0; base < N_NODES; base += 1024) {
        const int i = base + tid;
        const int v = (i < N_NODES) ? hist[i] : 0;
        int xx = v;
#pragma unroll
        for (int off = 1; off < 64; off <<= 1) {
            const int t = __shfl_up(xx, off, 64);
            if (lane >= off) xx += t;
        }
        if (lane == 63) wsum[wid] = xx;
        __syncthreads();
        if (wid == 0) {
            int ws = (lane < 16) ? wsum[lane] : 0;
#pragma unroll
            for (int off = 1; off < 16; off <<= 1) {
                const int t = __shfl_up(ws, off, 64);
                if (lane >= off) ws += t;
            }
            if (lane < 16) wsum[lane] = ws;   // inclusive wave sums
        }
        __syncthreads();
        const int wave_excl = (wid == 0) ? 0 : wsum[wid - 1];
        const int carry     = carry_s;
        if (i < N_NODES) cursor[i] = carry + wave_excl + xx - v;  // exclusive
        __syncthreads();
        if (tid == 0) carry_s = carry + wsum[15];
        __syncthreads();
    }
}

// ---------------------------------------------------------------------------
// Kernel 5: attention + scatter into dst-sorted order.
// sorted[pos] = (q0, q1, bitcast(src), 0)
// ---------------------------------------------------------------------------
__global__ void scatter_kernel(const int* __restrict__ ei,
                               const float2* __restrict__ s,
                               const float* __restrict__ c,
                               int* __restrict__ cursor,
                               float4* __restrict__ sorted) {
    const int e = blockIdx.x * blockDim.x + threadIdx.x;
    if (e >= E_TOT) return;
    int src, dst;
    if (e < N_EDGES) { src = ei[e]; dst = ei[N_EDGES + e]; }
    else             { src = dst = e - N_EDGES; }
    const float2 ss = s[src];
    const float2 sd = s[dst];
    const float l0 = ss.x - sd.x + c[0];
    const float l1 = ss.y - sd.y + c[1];
    const float m  = fmaxf(l0, l1);
    const float e0 = __expf(l0 - m);
    const float e1 = __expf(l1 - m);
    const float inv = 1.0f / (e0 + e1);
    const int pos = atomicAdd(&cursor[dst], 1);
    sorted[pos] = make_float4(e0 * inv, e1 * inv, __int_as_float(src), 0.f);
}

// ---------------------------------------------------------------------------
// Kernel 6: per-node aggregation + mean + bias + relu + residual.
// One wave per node; lane handles features {2l, 2l+1}. No atomics.
// After scatter, cursor[n] == segment end; start = end - hist[n].
// ---------------------------------------------------------------------------
__global__ __launch_bounds__(256) void agg_kernel(const float* __restrict__ x,
                                                  const float* __restrict__ bias,
                                                  const float* __restrict__ xw,
                                                  const float4* __restrict__ sorted,
                                                  const int* __restrict__ hist,
                                                  const int* __restrict__ cursor,
                                                  float* __restrict__ out) {
    const int lane = threadIdx.x & 63;
    const int n    = blockIdx.x * 4 + (threadIdx.x >> 6);
    if (n >= N_NODES) return;
    const int deg   = hist[n];      // >=1 (self loop)
    const int end   = cursor[n];
    const int start = end - deg;
    float accx = 0.f, accy = 0.f;
    for (int i = start; i < end; ++i) {
        const float4 d = sorted[i];                     // wave-uniform -> scalar
        const int src  = __float_as_int(d.z);
        const float* p = xw + (size_t)src * WCOLS + 2 * lane;
        const float2 a = *(const float2*)p;             // head 0
        const float2 b = *(const float2*)(p + F_OUT);   // head 1
        accx = fmaf(d.x, a.x, fmaf(d.y, b.x, accx));
        accy = fmaf(d.x, a.y, fmaf(d.y, b.y, accy));
    }
    const float inv = 1.0f / (float)deg;
    const float2 bv = *(const float2*)(bias + 2 * lane);
    const float2 xv = *(const float2*)(x + (size_t)n * F_IN + 2 * lane);
    float2 r;
    r.x = xv.x + fmaxf(fmaf(accx, inv, bv.x), 0.f);
    r.y = xv.y + fmaxf(fmaf(accy, inv, bv.y), 0.f);
    *(float2*)(out + (size_t)n * F_OUT + 2 * lane) = r;
}

// ---------------------------------------------------------------------------
extern "C" void kernel_launch(void* const* d_in, const int* in_sizes, int n_in,
                              void* d_out, int out_size, void* d_ws, size_t ws_size,
                              hipStream_t stream) {
    const float* x    = (const float*)d_in[0];
    const int*   ei   = (const int*)  d_in[1];   // [2, N_EDGES] flat
    const float* u    = (const float*)d_in[2];
    const float* c    = (const float*)d_in[3];
    const float* w    = (const float*)d_in[4];
    const float* bias = (const float*)d_in[5];
    float* out = (float*)d_out;

    // workspace layout (16B-aligned segments):
    //   xw     [N*256 f32]   51,200,000 B
    //   s      [N   f32x2]      400,000 B
    //   hist   [N   i32]        200,000 B
    //   cursor [N   i32]        200,000 B
    //   sorted [E_TOT f32x4] 13,600,000 B
    char* p = (char*)d_ws;
    float*  xw     = (float*)p;              p += (size_t)N_NODES * WCOLS * sizeof(float);
    float2* s      = (float2*)p;             p += (size_t)N_NODES * sizeof(float2);
    int*    hist   = (int*)p;                p += (size_t)N_NODES * sizeof(int);
    int*    cursor = (int*)p;                p += (size_t)N_NODES * sizeof(int);
    float4* sorted = (float4*)p;

    hipMemsetAsync(hist, 0, (size_t)N_NODES * sizeof(int), stream);

    // 1) xw = x @ w
    proj_kernel<<<N_NODES / ROWS_PER_BLOCK, 256, 0, stream>>>(x, w, xw);

    // 2) s = x @ u
    sproj_kernel<<<(N_NODES + 3) / 4, 256, 0, stream>>>(x, u, s);

    // 3) dst histogram (also the mean divisor)
    hist_kernel<<<(E_TOT + 255) / 256, 256, 0, stream>>>(ei, hist);

    // 4) exclusive scan -> cursor
    scan_kernel<<<1, 1024, 0, stream>>>(hist, cursor);

    // 5) attention + scatter into dst-sorted order
    scatter_kernel<<<(E_TOT + 255) / 256, 256, 0, stream>>>(ei, s, c, cursor, sorted);

    // 6) aggregate + finalize
    agg_kernel<<<(N_NODES + 3) / 4, 256, 0, stream>>>(x, bias, xw, sorted, hist, cursor, out);
}

// Round 4
// 303.739 us; speedup vs baseline: 3.1822x; 1.3501x over previous
//
#include <hip/hip_runtime.h>
#include <hip/hip_bf16.h>

// Problem constants (from reference setup_inputs)
constexpr int N_NODES = 50000;
constexpr int N_EDGES = 800000;
constexpr int E_TOT   = N_EDGES + N_NODES;   // with self loops
constexpr int F_IN    = 128;
constexpr int F_OUT   = 128;
constexpr int HEADS   = 2;
constexpr int WCOLS   = HEADS * F_OUT;       // 256

static __device__ __forceinline__ unsigned short f32_to_bf16_bits(float f) {
    unsigned int u = __float_as_uint(f);
    u += 0x7fffu + ((u >> 16) & 1u);   // round-to-nearest-even
    return (unsigned short)(u >> 16);
}

// ---------------------------------------------------------------------------
// Kernel 1: xwb = bf16(x @ w)   (x: [N,128], w: [128,256] -> xwb: [N,256] bf16)
// thread = column; x rows via wave-uniform scalar loads; w chunk of 8 in VGPRs
// (reused across 16 rows) so total register demand ~ acc16+wv8+addr < 48.
// ---------------------------------------------------------------------------
constexpr int ROWS_PER_BLOCK = 16;   // 50000 = 3125 * 16 exactly

__global__ __launch_bounds__(256) void proj_kernel(const float* __restrict__ x,
                                                   const float* __restrict__ w,
                                                   unsigned short* __restrict__ xwb) {
    const int col = threadIdx.x;                  // 0..255
    const int n0  = blockIdx.x * ROWS_PER_BLOCK;

    float acc[ROWS_PER_BLOCK];
#pragma unroll
    for (int r = 0; r < ROWS_PER_BLOCK; ++r) acc[r] = 0.f;

    for (int k0 = 0; k0 < F_IN; k0 += 8) {        // 16 iterations, NOT unrolled
        float wv[8];
#pragma unroll
        for (int i = 0; i < 8; ++i) wv[i] = w[(k0 + i) * WCOLS + col];
#pragma unroll
        for (int r = 0; r < ROWS_PER_BLOCK; ++r) {
            const float* xr = x + (size_t)(n0 + r) * F_IN + k0;   // uniform -> s_load
#pragma unroll
            for (int i = 0; i < 8; ++i) acc[r] = fmaf(xr[i], wv[i], acc[r]);
        }
    }
#pragma unroll
    for (int r = 0; r < ROWS_PER_BLOCK; ++r) {
        xwb[(size_t)(n0 + r) * WCOLS + col] = f32_to_bf16_bits(acc[r]);
    }
}

// ---------------------------------------------------------------------------
// Kernel 2: s[n,h] = x[n,:] . u[:,h]   (per-node attention projection)
// ---------------------------------------------------------------------------
__global__ __launch_bounds__(256) void sproj_kernel(const float* __restrict__ x,
                                                    const float* __restrict__ u,
                                                    float2* __restrict__ s) {
    const int lane = threadIdx.x & 63;
    const int n    = blockIdx.x * 4 + (threadIdx.x >> 6);
    if (n >= N_NODES) return;
    const float2 xv = *(const float2*)(x + (size_t)n * F_IN + 2 * lane);
    const float4 uv = *(const float4*)(u + 4 * lane);   // u[2l][0..1], u[2l+1][0..1]
    float p0 = xv.x * uv.x + xv.y * uv.z;
    float p1 = xv.x * uv.y + xv.y * uv.w;
#pragma unroll
    for (int off = 1; off < 64; off <<= 1) {
        p0 += __shfl_xor(p0, off, 64);
        p1 += __shfl_xor(p1, off, 64);
    }
    if (lane == 0) s[n] = make_float2(p0, p1);
}

// ---------------------------------------------------------------------------
// Kernel 3: histogram of destinations (this is also the mean-divisor "cnt")
// ---------------------------------------------------------------------------
__global__ void hist_kernel(const int* __restrict__ ei, int* __restrict__ hist) {
    const int e = blockIdx.x * blockDim.x + threadIdx.x;
    if (e >= E_TOT) return;
    const int dst = (e < N_EDGES) ? ei[N_EDGES + e] : (e - N_EDGES);
    atomicAdd(&hist[dst], 1);
}

// ---------------------------------------------------------------------------
// Kernels 4a/4b/4c: multi-block exclusive scan of hist -> cursor
// ---------------------------------------------------------------------------
constexpr int SCAN_BLOCK    = 1024;
constexpr int N_SCAN_BLOCKS = (N_NODES + SCAN_BLOCK - 1) / SCAN_BLOCK;  // 49

__global__ __launch_bounds__(1024) void scan_part(const int* __restrict__ hist,
                                                  int* __restrict__ cursor,
                                                  int* __restrict__ partials) {
    const int tid  = threadIdx.x;
    const int lane = tid & 63;
    const int wid  = tid >> 6;              // 0..15
    const int i    = blockIdx.x * SCAN_BLOCK + tid;
    const int v    = (i < N_NODES) ? hist[i] : 0;
    int xx = v;
#pragma unroll
    for (int off = 1; off < 64; off <<= 1) {
        const int t = __shfl_up(xx, off, 64);
        if (lane >= off) xx += t;
    }
    __shared__ int wsum[16];
    if (lane == 63) wsum[wid] = xx;
    __syncthreads();
    if (tid < 16) {                         // lanes 0..15 of wave 0
        int ws = wsum[tid];
#pragma unroll
        for (int off = 1; off < 16; off <<= 1) {
            const int t = __shfl_up(ws, off, 64);
            if (lane >= off) ws += t;
        }
        wsum[tid] = ws;                     // inclusive wave sums
    }
    __syncthreads();
    const int wexcl = wid ? wsum[wid - 1] : 0;
    if (i < N_NODES) cursor[i] = wexcl + xx - v;       // block-local exclusive
    if (tid == SCAN_BLOCK - 1) partials[blockIdx.x] = wexcl + xx;  // block total
}

__global__ __launch_bounds__(64) void scan_mid(int* __restrict__ partials) {
    const int lane = threadIdx.x;           // one wave, 49 values
    const int v = (lane < N_SCAN_BLOCKS) ? partials[lane] : 0;
    int xx = v;
#pragma unroll
    for (int off = 1; off < 64; off <<= 1) {
        const int t = __shfl_up(xx, off, 64);
        if (lane >= off) xx += t;
    }
    if (lane < N_SCAN_BLOCKS) partials[lane] = xx - v;  // exclusive
}

__global__ __launch_bounds__(1024) void scan_add(int* __restrict__ cursor,
                                                 const int* __restrict__ partials) {
    const int i = blockIdx.x * SCAN_BLOCK + threadIdx.x;
    if (i < N_NODES) cursor[i] += partials[blockIdx.x];
}

// ---------------------------------------------------------------------------
// Kernel 5: attention + scatter into dst-sorted order (8B records).
// rec = (bitcast(q0), src);  q1 = 1 - q0 reconstructed in agg.
// ---------------------------------------------------------------------------
__global__ void scatter_kernel(const int* __restrict__ ei,
                               const float2* __restrict__ s,
                               const float* __restrict__ c,
                               int* __restrict__ cursor,
                               int2* __restrict__ sorted) {
    const int e = blockIdx.x * blockDim.x + threadIdx.x;
    if (e >= E_TOT) return;
    int src, dst;
    if (e < N_EDGES) { src = ei[e]; dst = ei[N_EDGES + e]; }
    else             { src = dst = e - N_EDGES; }
    const float2 ss = s[src];
    const float2 sd = s[dst];
    const float l0 = ss.x - sd.x + c[0];
    const float l1 = ss.y - sd.y + c[1];
    const float m  = fmaxf(l0, l1);
    const float e0 = __expf(l0 - m);
    const float e1 = __expf(l1 - m);
    const float q0 = e0 / (e0 + e1);
    const int pos = atomicAdd(&cursor[dst], 1);
    sorted[pos] = make_int2(__float_as_int(q0), src);
}

// ---------------------------------------------------------------------------
// Kernel 6: per-node aggregation + mean + bias + relu + residual.
// One wave per node; lane handles out-features {2l, 2l+1}; xw gathered as bf16.
// After scatter, cursor[n] == segment end; start = end - hist[n].
// ---------------------------------------------------------------------------
__global__ __launch_bounds__(256) void agg_kernel(const float* __restrict__ x,
                                                  const float* __restrict__ bias,
                                                  const unsigned short* __restrict__ xwb,
                                                  const int2* __restrict__ sorted,
                                                  const int* __restrict__ hist,
                                                  const int* __restrict__ cursor,
                                                  float* __restrict__ out) {
    const int lane = threadIdx.x & 63;
    const int n    = blockIdx.x * 4 + (threadIdx.x >> 6);
    if (n >= N_NODES) return;
    const int deg   = hist[n];      // >=1 (self loop)
    const int end   = cursor[n];
    const int start = end - deg;
    float accx = 0.f, accy = 0.f;
    for (int i = start; i < end; ++i) {
        const int2 d   = sorted[i];                    // wave-uniform -> scalar
        const float q0 = __int_as_float(d.x);
        const float q1 = 1.0f - q0;
        const int  src = d.y;
        const unsigned int* p = (const unsigned int*)(xwb + (size_t)src * WCOLS + 2 * lane);
        const unsigned int h0 = p[0];                  // head0 feats {2l,2l+1}
        const unsigned int h1 = p[F_OUT / 2];          // head1 feats (offset 128 elems)
        const float a0 = __uint_as_float(h0 << 16);
        const float a1 = __uint_as_float(h0 & 0xffff0000u);
        const float b0 = __uint_as_float(h1 << 16);
        const float b1 = __uint_as_float(h1 & 0xffff0000u);
        accx = fmaf(q0, a0, fmaf(q1, b0, accx));
        accy = fmaf(q0, a1, fmaf(q1, b1, accy));
    }
    const float inv = 1.0f / (float)deg;
    const float2 bv = *(const float2*)(bias + 2 * lane);
    const float2 xv = *(const float2*)(x + (size_t)n * F_IN + 2 * lane);
    float2 r;
    r.x = xv.x + fmaxf(fmaf(accx, inv, bv.x), 0.f);
    r.y = xv.y + fmaxf(fmaf(accy, inv, bv.y), 0.f);
    *(float2*)(out + (size_t)n * F_OUT + 2 * lane) = r;
}

// ---------------------------------------------------------------------------
extern "C" void kernel_launch(void* const* d_in, const int* in_sizes, int n_in,
                              void* d_out, int out_size, void* d_ws, size_t ws_size,
                              hipStream_t stream) {
    const float* x    = (const float*)d_in[0];
    const int*   ei   = (const int*)  d_in[1];   // [2, N_EDGES] flat
    const float* u    = (const float*)d_in[2];
    const float* c    = (const float*)d_in[3];
    const float* w    = (const float*)d_in[4];
    const float* bias = (const float*)d_in[5];
    float* out = (float*)d_out;

    // workspace layout (16B-aligned segments):
    //   xwb      [N*256 bf16]  25,600,000 B
    //   s        [N   f32x2]      400,000 B
    //   hist     [N   i32]        200,000 B
    //   cursor   [N   i32]        200,000 B
    //   partials [64  i32]            256 B
    //   sorted   [E_TOT int2]   6,800,000 B
    char* p = (char*)d_ws;
    unsigned short* xwb = (unsigned short*)p;  p += (size_t)N_NODES * WCOLS * sizeof(unsigned short);
    float2* s      = (float2*)p;               p += (size_t)N_NODES * sizeof(float2);
    int*    hist   = (int*)p;                  p += (size_t)N_NODES * sizeof(int);
    int*    cursor = (int*)p;                  p += (size_t)N_NODES * sizeof(int);
    int*    partials = (int*)p;                p += 256;
    int2*   sorted = (int2*)p;

    hipMemsetAsync(hist, 0, (size_t)N_NODES * sizeof(int), stream);

    // 1) xwb = bf16(x @ w)
    proj_kernel<<<N_NODES / ROWS_PER_BLOCK, 256, 0, stream>>>(x, w, xwb);

    // 2) s = x @ u
    sproj_kernel<<<(N_NODES + 3) / 4, 256, 0, stream>>>(x, u, s);

    // 3) dst histogram (also the mean divisor)
    hist_kernel<<<(E_TOT + 255) / 256, 256, 0, stream>>>(ei, hist);

    // 4) exclusive scan -> cursor (3-phase multi-block)
    scan_part<<<N_SCAN_BLOCKS, SCAN_BLOCK, 0, stream>>>(hist, cursor, partials);
    scan_mid<<<1, 64, 0, stream>>>(partials);
    scan_add<<<N_SCAN_BLOCKS, SCAN_BLOCK, 0, stream>>>(cursor, partials);

    // 5) attention + scatter into dst-sorted order
    scatter_kernel<<<(E_TOT + 255) / 256, 256, 0, stream>>>(ei, s, c, cursor, sorted);

    // 6) aggregate + finalize
    agg_kernel<<<(N_NODES + 3) / 4, 256, 0, stream>>>(x, bias, xwb, sorted, hist, cursor, out);
}

// Round 5
// 244.787 us; speedup vs baseline: 3.9485x; 1.2408x over previous
//
#include <hip/hip_runtime.h>
#include <hip/hip_bf16.h>

// Problem constants (from reference setup_inputs)
constexpr int N_NODES = 50000;
constexpr int N_EDGES = 800000;
constexpr int E_TOT   = N_EDGES + N_NODES;   // with self loops
constexpr int F_IN    = 128;
constexpr int F_OUT   = 128;
constexpr int HEADS   = 2;
constexpr int WCOLS   = HEADS * F_OUT;       // 256

typedef __attribute__((ext_vector_type(8))) short  bf16x8;   // MFMA A/B frag (4 VGPR)
typedef __attribute__((ext_vector_type(4))) float  f32x4;    // MFMA C/D frag
typedef __attribute__((ext_vector_type(4))) unsigned short u16x4;

static __device__ __forceinline__ unsigned short f32_to_bf16_bits(float f) {
    unsigned int u = __float_as_uint(f);
    u += 0x7fffu + ((u >> 16) & 1u);   // round-to-nearest-even
    return (unsigned short)(u >> 16);
}

// ---------------------------------------------------------------------------
// Kernel 0: wT[n][k] = bf16(w[k][n])   (w: [128,256] f32 -> wT: [256,128] bf16)
// ---------------------------------------------------------------------------
__global__ __launch_bounds__(256) void wt_kernel(const float* __restrict__ w,
                                                 unsigned short* __restrict__ wT) {
    const int tid = blockIdx.x * 256 + threadIdx.x;   // 0..32767
    const int k = tid >> 8;          // 0..127
    const int n = tid & 255;         // 0..255
    wT[n * F_IN + k] = f32_to_bf16_bits(w[k * WCOLS + n]);
}

// ---------------------------------------------------------------------------
// Kernel 1: xwb = bf16(x @ w) via MFMA.
// Block = 256 thr = 4 waves; block covers 16 x-rows, wave wv covers cols
// [64*wv, 64*wv+64) as 4 16x16 tiles. D = mfma(w_frag, x_frag): D "col"
// (lane&15) = x-row, D "row" ((lane>>4)*4+reg) = w-col -> 8B packed stores.
// ---------------------------------------------------------------------------
__global__ __launch_bounds__(256) void proj_kernel(const float* __restrict__ x,
                                                   const unsigned short* __restrict__ wT,
                                                   unsigned short* __restrict__ xwb) {
    const int lane = threadIdx.x & 63;
    const int wv   = threadIdx.x >> 6;        // 0..3
    const int n0   = blockIdx.x * 16;         // x-row base (50000 = 3125*16)
    const int l15  = lane & 15;
    const int kg   = lane >> 4;               // 0..3 (k-group)

    f32x4 acc0 = {0.f,0.f,0.f,0.f}, acc1 = acc0, acc2 = acc0, acc3 = acc0;

#pragma unroll
    for (int ks = 0; ks < 4; ++ks) {          // K = 4 * 32
        // B operand: x rows. lane: row = n0+l15, k = ks*32 + kg*8 .. +7 (f32 -> bf16)
        const float* xp = x + (size_t)(n0 + l15) * F_IN + ks * 32 + kg * 8;
        const float4 xa = *(const float4*)xp;
        const float4 xb = *(const float4*)(xp + 4);
        bf16x8 xf;
        xf[0] = (short)f32_to_bf16_bits(xa.x);
        xf[1] = (short)f32_to_bf16_bits(xa.y);
        xf[2] = (short)f32_to_bf16_bits(xa.z);
        xf[3] = (short)f32_to_bf16_bits(xa.w);
        xf[4] = (short)f32_to_bf16_bits(xb.x);
        xf[5] = (short)f32_to_bf16_bits(xb.y);
        xf[6] = (short)f32_to_bf16_bits(xb.z);
        xf[7] = (short)f32_to_bf16_bits(xb.w);

        // A operand: w cols (from wT, k-contiguous). col = wv*64 + t*16 + l15
        const unsigned short* wbase = wT + (size_t)(wv * 64 + l15) * F_IN + ks * 32 + kg * 8;
        const bf16x8 wf0 = *(const bf16x8*)(wbase);
        const bf16x8 wf1 = *(const bf16x8*)(wbase + 16 * F_IN);
        const bf16x8 wf2 = *(const bf16x8*)(wbase + 32 * F_IN);
        const bf16x8 wf3 = *(const bf16x8*)(wbase + 48 * F_IN);

        acc0 = __builtin_amdgcn_mfma_f32_16x16x32_bf16(wf0, xf, acc0, 0, 0, 0);
        acc1 = __builtin_amdgcn_mfma_f32_16x16x32_bf16(wf1, xf, acc1, 0, 0, 0);
        acc2 = __builtin_amdgcn_mfma_f32_16x16x32_bf16(wf2, xf, acc2, 0, 0, 0);
        acc3 = __builtin_amdgcn_mfma_f32_16x16x32_bf16(wf3, xf, acc3, 0, 0, 0);
    }

    // Store: lane writes row n0+l15, cols wv*64 + t*16 + kg*4 + [0..3] as 4 bf16 (8B)
    unsigned short* orow = xwb + (size_t)(n0 + l15) * WCOLS + wv * 64 + kg * 4;
    const f32x4 a[4] = {acc0, acc1, acc2, acc3};
#pragma unroll
    for (int t = 0; t < 4; ++t) {
        u16x4 pk;
        pk[0] = f32_to_bf16_bits(a[t][0]);
        pk[1] = f32_to_bf16_bits(a[t][1]);
        pk[2] = f32_to_bf16_bits(a[t][2]);
        pk[3] = f32_to_bf16_bits(a[t][3]);
        *(u16x4*)(orow + t * 16) = pk;
    }
}

// ---------------------------------------------------------------------------
// Kernel 2: s[n,h] = x[n,:] . u[:,h]   (per-node attention projection)
// ---------------------------------------------------------------------------
__global__ __launch_bounds__(256) void sproj_kernel(const float* __restrict__ x,
                                                    const float* __restrict__ u,
                                                    float2* __restrict__ s) {
    const int lane = threadIdx.x & 63;
    const int n    = blockIdx.x * 4 + (threadIdx.x >> 6);
    if (n >= N_NODES) return;
    const float2 xv = *(const float2*)(x + (size_t)n * F_IN + 2 * lane);
    const float4 uv = *(const float4*)(u + 4 * lane);   // u[2l][0..1], u[2l+1][0..1]
    float p0 = xv.x * uv.x + xv.y * uv.z;
    float p1 = xv.x * uv.y + xv.y * uv.w;
#pragma unroll
    for (int off = 1; off < 64; off <<= 1) {
        p0 += __shfl_xor(p0, off, 64);
        p1 += __shfl_xor(p1, off, 64);
    }
    if (lane == 0) s[n] = make_float2(p0, p1);
}

// ---------------------------------------------------------------------------
// Kernel 3: histogram of destinations (this is also the mean-divisor "cnt")
// ---------------------------------------------------------------------------
__global__ void hist_kernel(const int* __restrict__ ei, int* __restrict__ hist) {
    const int e = blockIdx.x * blockDim.x + threadIdx.x;
    if (e >= E_TOT) return;
    const int dst = (e < N_EDGES) ? ei[N_EDGES + e] : (e - N_EDGES);
    atomicAdd(&hist[dst], 1);
}

// ---------------------------------------------------------------------------
// Kernels 4a/4b/4c: multi-block exclusive scan of hist -> cursor
// ---------------------------------------------------------------------------
constexpr int SCAN_BLOCK    = 1024;
constexpr int N_SCAN_BLOCKS = (N_NODES + SCAN_BLOCK - 1) / SCAN_BLOCK;  // 49

__global__ __launch_bounds__(1024) void scan_part(const int* __restrict__ hist,
                                                  int* __restrict__ cursor,
                                                  int* __restrict__ partials) {
    const int tid  = threadIdx.x;
    const int lane = tid & 63;
    const int wid  = tid >> 6;              // 0..15
    const int i    = blockIdx.x * SCAN_BLOCK + tid;
    const int v    = (i < N_NODES) ? hist[i] : 0;
    int xx = v;
#pragma unroll
    for (int off = 1; off < 64; off <<= 1) {
        const int t = __shfl_up(xx, off, 64);
        if (lane >= off) xx += t;
    }
    __shared__ int wsum[16];
    if (lane == 63) wsum[wid] = xx;
    __syncthreads();
    if (tid < 16) {                         // lanes 0..15 of wave 0
        int ws = wsum[tid];
#pragma unroll
        for (int off = 1; off < 16; off <<= 1) {
            const int t = __shfl_up(ws, off, 64);
            if (lane >= off) ws += t;
        }
        wsum[tid] = ws;                     // inclusive wave sums
    }
    __syncthreads();
    const int wexcl = wid ? wsum[wid - 1] : 0;
    if (i < N_NODES) cursor[i] = wexcl + xx - v;       // block-local exclusive
    if (tid == SCAN_BLOCK - 1) partials[blockIdx.x] = wexcl + xx;  // block total
}

__global__ __launch_bounds__(64) void scan_mid(int* __restrict__ partials) {
    const int lane = threadIdx.x;           // one wave, 49 values
    const int v = (lane < N_SCAN_BLOCKS) ? partials[lane] : 0;
    int xx = v;
#pragma unroll
    for (int off = 1; off < 64; off <<= 1) {
        const int t = __shfl_up(xx, off, 64);
        if (lane >= off) xx += t;
    }
    if (lane < N_SCAN_BLOCKS) partials[lane] = xx - v;  // exclusive
}

__global__ __launch_bounds__(1024) void scan_add(int* __restrict__ cursor,
                                                 const int* __restrict__ partials) {
    const int i = blockIdx.x * SCAN_BLOCK + threadIdx.x;
    if (i < N_NODES) cursor[i] += partials[blockIdx.x];
}

// ---------------------------------------------------------------------------
// Kernel 5: attention + scatter into dst-sorted order (8B records).
// rec = (bitcast(q0), src);  q1 = 1 - q0 reconstructed in agg.
// ---------------------------------------------------------------------------
__global__ void scatter_kernel(const int* __restrict__ ei,
                               const float2* __restrict__ s,
                               const float* __restrict__ c,
                               int* __restrict__ cursor,
                               int2* __restrict__ sorted) {
    const int e = blockIdx.x * blockDim.x + threadIdx.x;
    if (e >= E_TOT) return;
    int src, dst;
    if (e < N_EDGES) { src = ei[e]; dst = ei[N_EDGES + e]; }
    else             { src = dst = e - N_EDGES; }
    const float2 ss = s[src];
    const float2 sd = s[dst];
    const float l0 = ss.x - sd.x + c[0];
    const float l1 = ss.y - sd.y + c[1];
    const float m  = fmaxf(l0, l1);
    const float e0 = __expf(l0 - m);
    const float e1 = __expf(l1 - m);
    const float q0 = e0 / (e0 + e1);
    const int pos = atomicAdd(&cursor[dst], 1);
    sorted[pos] = make_int2(__float_as_int(q0), src);
}

// ---------------------------------------------------------------------------
// Kernel 6: per-node aggregation + mean + bias + relu + residual.
// One wave per node; lane handles out-features {2l, 2l+1}; xw gathered as bf16.
// After scatter, cursor[n] == segment end; start = end - hist[n].
// ---------------------------------------------------------------------------
__global__ __launch_bounds__(256) void agg_kernel(const float* __restrict__ x,
                                                  const float* __restrict__ bias,
                                                  const unsigned short* __restrict__ xwb,
                                                  const int2* __restrict__ sorted,
                                                  const int* __restrict__ hist,
                                                  const int* __restrict__ cursor,
                                                  float* __restrict__ out) {
    const int lane = threadIdx.x & 63;
    const int n    = blockIdx.x * 4 + (threadIdx.x >> 6);
    if (n >= N_NODES) return;
    const int deg   = hist[n];      // >=1 (self loop)
    const int end   = cursor[n];
    const int start = end - deg;
    float accx = 0.f, accy = 0.f;
    for (int i = start; i < end; ++i) {
        const int2 d   = sorted[i];                    // wave-uniform -> scalar
        const float q0 = __int_as_float(d.x);
        const float q1 = 1.0f - q0;
        const int  src = d.y;
        const unsigned int* p = (const unsigned int*)(xwb + (size_t)src * WCOLS + 2 * lane);
        const unsigned int h0 = p[0];                  // head0 feats {2l,2l+1}
        const unsigned int h1 = p[F_OUT / 2];          // head1 feats (offset 128 elems)
        const float a0 = __uint_as_float(h0 << 16);
        const float a1 = __uint_as_float(h0 & 0xffff0000u);
        const float b0 = __uint_as_float(h1 << 16);
        const float b1 = __uint_as_float(h1 & 0xffff0000u);
        accx = fmaf(q0, a0, fmaf(q1, b0, accx));
        accy = fmaf(q0, a1, fmaf(q1, b1, accy));
    }
    const float inv = 1.0f / (float)deg;
    const float2 bv = *(const float2*)(bias + 2 * lane);
    const float2 xv = *(const float2*)(x + (size_t)n * F_IN + 2 * lane);
    float2 r;
    r.x = xv.x + fmaxf(fmaf(accx, inv, bv.x), 0.f);
    r.y = xv.y + fmaxf(fmaf(accy, inv, bv.y), 0.f);
    *(float2*)(out + (size_t)n * F_OUT + 2 * lane) = r;
}

// ---------------------------------------------------------------------------
extern "C" void kernel_launch(void* const* d_in, const int* in_sizes, int n_in,
                              void* d_out, int out_size, void* d_ws, size_t ws_size,
                              hipStream_t stream) {
    const float* x    = (const float*)d_in[0];
    const int*   ei   = (const int*)  d_in[1];   // [2, N_EDGES] flat
    const float* u    = (const float*)d_in[2];
    const float* c    = (const float*)d_in[3];
    const float* w    = (const float*)d_in[4];
    const float* bias = (const float*)d_in[5];
    float* out = (float*)d_out;

    // workspace layout (16B-aligned segments):
    //   xwb      [N*256 bf16]  25,600,000 B
    //   s        [N   f32x2]      400,000 B
    //   hist     [N   i32]        200,000 B
    //   cursor   [N   i32]        200,000 B
    //   partials [64  i32]            256 B
    //   wT       [256*128 bf16]    65,536 B
    //   sorted   [E_TOT int2]   6,800,000 B
    char* p = (char*)d_ws;
    unsigned short* xwb = (unsigned short*)p;  p += (size_t)N_NODES * WCOLS * sizeof(unsigned short);
    float2* s      = (float2*)p;               p += (size_t)N_NODES * sizeof(float2);
    int*    hist   = (int*)p;                  p += (size_t)N_NODES * sizeof(int);
    int*    cursor = (int*)p;                  p += (size_t)N_NODES * sizeof(int);
    int*    partials = (int*)p;                p += 256;
    unsigned short* wT = (unsigned short*)p;   p += (size_t)WCOLS * F_IN * sizeof(unsigned short);
    int2*   sorted = (int2*)p;

    hipMemsetAsync(hist, 0, (size_t)N_NODES * sizeof(int), stream);

    // 0) wT = bf16(w^T)
    wt_kernel<<<(WCOLS * F_IN) / 256, 256, 0, stream>>>(w, wT);

    // 1) xwb = bf16(x @ w)  (MFMA)
    proj_kernel<<<N_NODES / 16, 256, 0, stream>>>(x, wT, xwb);

    // 2) s = x @ u
    sproj_kernel<<<(N_NODES + 3) / 4, 256, 0, stream>>>(x, u, s);

    // 3) dst histogram (also the mean divisor)
    hist_kernel<<<(E_TOT + 255) / 256, 256, 0, stream>>>(ei, hist);

    // 4) exclusive scan -> cursor (3-phase multi-block)
    scan_part<<<N_SCAN_BLOCKS, SCAN_BLOCK, 0, stream>>>(hist, cursor, partials);
    scan_mid<<<1, 64, 0, stream>>>(partials);
    scan_add<<<N_SCAN_BLOCKS, SCAN_BLOCK, 0, stream>>>(cursor, partials);

    // 5) attention + scatter into dst-sorted order
    scatter_kernel<<<(E_TOT + 255) / 256, 256, 0, stream>>>(ei, s, c, cursor, sorted);

    // 6) aggregate + finalize
    agg_kernel<<<(N_NODES + 3) / 4, 256, 0, stream>>>(x, bias, xwb, sorted, hist, cursor, out);
}

// Round 6
// 212.365 us; speedup vs baseline: 4.5513x; 1.1527x over previous
//
#include <hip/hip_runtime.h>
#include <hip/hip_bf16.h>

// Problem constants (from reference setup_inputs)
constexpr int N_NODES = 50000;
constexpr int N_EDGES = 800000;
constexpr int E_TOT   = N_EDGES + N_NODES;   // with self loops
constexpr int F_IN    = 128;
constexpr int F_OUT   = 128;
constexpr int HEADS   = 2;
constexpr int WCOLS   = HEADS * F_OUT;       // 256

typedef __attribute__((ext_vector_type(8))) short  bf16x8;   // MFMA A/B frag (4 VGPR)
typedef __attribute__((ext_vector_type(4))) float  f32x4;    // MFMA C/D frag
typedef __attribute__((ext_vector_type(4))) unsigned short u16x4;

static __device__ __forceinline__ unsigned short f32_to_bf16_bits(float f) {
    unsigned int u = __float_as_uint(f);
    u += 0x7fffu + ((u >> 16) & 1u);   // round-to-nearest-even
    return (unsigned short)(u >> 16);
}
static __device__ __forceinline__ float bf16_bits_to_f32(unsigned short b) {
    return __uint_as_float(((unsigned int)b) << 16);
}

// ---------------------------------------------------------------------------
// Kernel 0: wT[n][k] = bf16(w[k][n])   (w: [128,256] f32 -> wT: [256,128] bf16)
// ---------------------------------------------------------------------------
__global__ __launch_bounds__(256) void wt_kernel(const float* __restrict__ w,
                                                 unsigned short* __restrict__ wT) {
    const int tid = blockIdx.x * 256 + threadIdx.x;   // 0..32767
    const int k = tid >> 8;          // 0..127
    const int n = tid & 255;         // 0..255
    wT[n * F_IN + k] = f32_to_bf16_bits(w[k * WCOLS + n]);
}

// ---------------------------------------------------------------------------
// Kernel 1: xwb = bf16(x @ w) via MFMA.
// Block = 256 thr = 4 waves; block covers 16 x-rows, wave wv covers cols
// [64*wv, 64*wv+64) as 4 16x16 tiles. D = mfma(w_frag, x_frag): D "col"
// (lane&15) = x-row, D "row" ((lane>>4)*4+reg) = w-col -> 8B packed stores.
// ---------------------------------------------------------------------------
__global__ __launch_bounds__(256) void proj_kernel(const float* __restrict__ x,
                                                   const unsigned short* __restrict__ wT,
                                                   unsigned short* __restrict__ xwb) {
    const int lane = threadIdx.x & 63;
    const int wv   = threadIdx.x >> 6;        // 0..3
    const int n0   = blockIdx.x * 16;         // x-row base (50000 = 3125*16)
    const int l15  = lane & 15;
    const int kg   = lane >> 4;               // 0..3 (k-group)

    f32x4 acc0 = {0.f,0.f,0.f,0.f}, acc1 = acc0, acc2 = acc0, acc3 = acc0;

#pragma unroll
    for (int ks = 0; ks < 4; ++ks) {          // K = 4 * 32
        // B operand: x rows. lane: row = n0+l15, k = ks*32 + kg*8 .. +7 (f32 -> bf16)
        const float* xp = x + (size_t)(n0 + l15) * F_IN + ks * 32 + kg * 8;
        const float4 xa = *(const float4*)xp;
        const float4 xb = *(const float4*)(xp + 4);
        bf16x8 xf;
        xf[0] = (short)f32_to_bf16_bits(xa.x);
        xf[1] = (short)f32_to_bf16_bits(xa.y);
        xf[2] = (short)f32_to_bf16_bits(xa.z);
        xf[3] = (short)f32_to_bf16_bits(xa.w);
        xf[4] = (short)f32_to_bf16_bits(xb.x);
        xf[5] = (short)f32_to_bf16_bits(xb.y);
        xf[6] = (short)f32_to_bf16_bits(xb.z);
        xf[7] = (short)f32_to_bf16_bits(xb.w);

        // A operand: w cols (from wT, k-contiguous). col = wv*64 + t*16 + l15
        const unsigned short* wbase = wT + (size_t)(wv * 64 + l15) * F_IN + ks * 32 + kg * 8;
        const bf16x8 wf0 = *(const bf16x8*)(wbase);
        const bf16x8 wf1 = *(const bf16x8*)(wbase + 16 * F_IN);
        const bf16x8 wf2 = *(const bf16x8*)(wbase + 32 * F_IN);
        const bf16x8 wf3 = *(const bf16x8*)(wbase + 48 * F_IN);

        acc0 = __builtin_amdgcn_mfma_f32_16x16x32_bf16(wf0, xf, acc0, 0, 0, 0);
        acc1 = __builtin_amdgcn_mfma_f32_16x16x32_bf16(wf1, xf, acc1, 0, 0, 0);
        acc2 = __builtin_amdgcn_mfma_f32_16x16x32_bf16(wf2, xf, acc2, 0, 0, 0);
        acc3 = __builtin_amdgcn_mfma_f32_16x16x32_bf16(wf3, xf, acc3, 0, 0, 0);
    }

    // Store: lane writes row n0+l15, cols wv*64 + t*16 + kg*4 + [0..3] as 4 bf16 (8B)
    unsigned short* orow = xwb + (size_t)(n0 + l15) * WCOLS + wv * 64 + kg * 4;
    const f32x4 a[4] = {acc0, acc1, acc2, acc3};
#pragma unroll
    for (int t = 0; t < 4; ++t) {
        u16x4 pk;
        pk[0] = f32_to_bf16_bits(a[t][0]);
        pk[1] = f32_to_bf16_bits(a[t][1]);
        pk[2] = f32_to_bf16_bits(a[t][2]);
        pk[3] = f32_to_bf16_bits(a[t][3]);
        *(u16x4*)(orow + t * 16) = pk;
    }
}

// ---------------------------------------------------------------------------
// Kernel 2: s[n,h] = x[n,:] . u[:,h]   (per-node attention projection)
// ---------------------------------------------------------------------------
__global__ __launch_bounds__(256) void sproj_kernel(const float* __restrict__ x,
                                                    const float* __restrict__ u,
                                                    float2* __restrict__ s) {
    const int lane = threadIdx.x & 63;
    const int n    = blockIdx.x * 4 + (threadIdx.x >> 6);
    if (n >= N_NODES) return;
    const float2 xv = *(const float2*)(x + (size_t)n * F_IN + 2 * lane);
    const float4 uv = *(const float4*)(u + 4 * lane);   // u[2l][0..1], u[2l+1][0..1]
    float p0 = xv.x * uv.x + xv.y * uv.z;
    float p1 = xv.x * uv.y + xv.y * uv.w;
#pragma unroll
    for (int off = 1; off < 64; off <<= 1) {
        p0 += __shfl_xor(p0, off, 64);
        p1 += __shfl_xor(p1, off, 64);
    }
    if (lane == 0) s[n] = make_float2(p0, p1);
}

// ---------------------------------------------------------------------------
// Kernel 3a: hist[n] = 1 (self loop pre-counted; replaces memset)
// Kernel 3b: histogram of real-edge destinations
// ---------------------------------------------------------------------------
__global__ __launch_bounds__(256) void hist_init(int* __restrict__ hist) {
    const int n = blockIdx.x * 256 + threadIdx.x;
    if (n < N_NODES) hist[n] = 1;
}

__global__ void hist_kernel(const int* __restrict__ ei, int* __restrict__ hist) {
    const int e = blockIdx.x * blockDim.x + threadIdx.x;
    if (e >= N_EDGES) return;
    atomicAdd(&hist[ei[N_EDGES + e]], 1);
}

// ---------------------------------------------------------------------------
// Kernels 4a/4b/4c: multi-block exclusive scan of hist -> cursor.
// scan_add shifts by +1: slot `start` of each segment is reserved for the
// self-loop record (placed deterministically by self_place, no atomic).
// ---------------------------------------------------------------------------
constexpr int SCAN_BLOCK    = 1024;
constexpr int N_SCAN_BLOCKS = (N_NODES + SCAN_BLOCK - 1) / SCAN_BLOCK;  // 49

__global__ __launch_bounds__(1024) void scan_part(const int* __restrict__ hist,
                                                  int* __restrict__ cursor,
                                                  int* __restrict__ partials) {
    const int tid  = threadIdx.x;
    const int lane = tid & 63;
    const int wid  = tid >> 6;              // 0..15
    const int i    = blockIdx.x * SCAN_BLOCK + tid;
    const int v    = (i < N_NODES) ? hist[i] : 0;
    int xx = v;
#pragma unroll
    for (int off = 1; off < 64; off <<= 1) {
        const int t = __shfl_up(xx, off, 64);
        if (lane >= off) xx += t;
    }
    __shared__ int wsum[16];
    if (lane == 63) wsum[wid] = xx;
    __syncthreads();
    if (tid < 16) {                         // lanes 0..15 of wave 0
        int ws = wsum[tid];
#pragma unroll
        for (int off = 1; off < 16; off <<= 1) {
            const int t = __shfl_up(ws, off, 64);
            if (lane >= off) ws += t;
        }
        wsum[tid] = ws;                     // inclusive wave sums
    }
    __syncthreads();
    const int wexcl = wid ? wsum[wid - 1] : 0;
    if (i < N_NODES) cursor[i] = wexcl + xx - v;       // block-local exclusive
    if (tid == SCAN_BLOCK - 1) partials[blockIdx.x] = wexcl + xx;  // block total
}

__global__ __launch_bounds__(64) void scan_mid(int* __restrict__ partials) {
    const int lane = threadIdx.x;           // one wave, 49 values
    const int v = (lane < N_SCAN_BLOCKS) ? partials[lane] : 0;
    int xx = v;
#pragma unroll
    for (int off = 1; off < 64; off <<= 1) {
        const int t = __shfl_up(xx, off, 64);
        if (lane >= off) xx += t;
    }
    if (lane < N_SCAN_BLOCKS) partials[lane] = xx - v;  // exclusive
}

__global__ __launch_bounds__(1024) void scan_add(int* __restrict__ cursor,
                                                 const int* __restrict__ partials) {
    const int i = blockIdx.x * SCAN_BLOCK + threadIdx.x;
    if (i < N_NODES) cursor[i] += partials[blockIdx.x] + 1;   // +1: reserve self slot
}

// ---------------------------------------------------------------------------
// Kernel 4d: place self-loop records (q is the same constant softmax(c)).
// Runs BEFORE scatter: cursor[n] == start+1, slot `start` never touched by it.
// ---------------------------------------------------------------------------
__global__ __launch_bounds__(256) void self_place(const float* __restrict__ c,
                                                  const int* __restrict__ cursor,
                                                  int2* __restrict__ sorted) {
    const int n = blockIdx.x * 256 + threadIdx.x;
    if (n >= N_NODES) return;
    const float c0 = c[0], c1 = c[1];
    const float m  = fmaxf(c0, c1);
    const float e0 = __expf(c0 - m);
    const float e1 = __expf(c1 - m);
    const float q0 = e0 / (e0 + e1);
    sorted[cursor[n] - 1] = make_int2(__float_as_int(q0), n);
}

// ---------------------------------------------------------------------------
// Kernel 5: attention + scatter into dst-sorted order (8B records, real edges).
// rec = (bitcast(q0), src);  q1 = 1 - q0 reconstructed in agg.
// ---------------------------------------------------------------------------
__global__ void scatter_kernel(const int* __restrict__ ei,
                               const float2* __restrict__ s,
                               const float* __restrict__ c,
                               int* __restrict__ cursor,
                               int2* __restrict__ sorted) {
    const int e = blockIdx.x * blockDim.x + threadIdx.x;
    if (e >= N_EDGES) return;
    const int src = ei[e];
    const int dst = ei[N_EDGES + e];
    const float2 ss = s[src];
    const float2 sd = s[dst];
    const float l0 = ss.x - sd.x + c[0];
    const float l1 = ss.y - sd.y + c[1];
    const float m  = fmaxf(l0, l1);
    const float e0 = __expf(l0 - m);
    const float e1 = __expf(l1 - m);
    const float q0 = e0 / (e0 + e1);
    const int pos = atomicAdd(&cursor[dst], 1);
    sorted[pos] = make_int2(__float_as_int(q0), src);
}

// ---------------------------------------------------------------------------
// Kernel 6: per-node aggregation + mean + bias + relu + residual.
// One wave per node. Half-wave head split: lanes 0-31 gather head0 bytes,
// lanes 32-63 head1 of the SAME features; per-lane q = base + sign*q0.
// 4x unrolled -> 4 records + 4 row-gathers in flight. One shfl_xor(32) fold
// after the loop. Lanes 0-31 write the final float4.
// ---------------------------------------------------------------------------
__global__ __launch_bounds__(256) void agg_kernel(const float* __restrict__ x,
                                                  const float* __restrict__ bias,
                                                  const unsigned short* __restrict__ xwb,
                                                  const int2* __restrict__ sorted,
                                                  const int* __restrict__ hist,
                                                  const int* __restrict__ cursor,
                                                  float* __restrict__ out) {
    const int lane = threadIdx.x & 63;
    const int half = lane >> 5;          // 0: head0, 1: head1
    const int l5   = lane & 31;          // feature group: feats 4*l5 .. 4*l5+3
    const int n    = blockIdx.x * 4 + (threadIdx.x >> 6);
    if (n >= N_NODES) return;
    const int deg   = hist[n];           // >=1 (self loop)
    const int end   = cursor[n];
    const int start = end - deg;

    const float qbase = half ? 1.0f : 0.0f;
    const float qsign = half ? -1.0f : 1.0f;
    const unsigned short* gb = xwb + half * F_OUT + 4 * l5;

    float4 a0 = {0.f,0.f,0.f,0.f}, a1 = a0, a2 = a0, a3 = a0;
    int j = start;
    for (; j + 4 <= end; j += 4) {
        const int2 r0 = sorted[j];
        const int2 r1 = sorted[j + 1];
        const int2 r2 = sorted[j + 2];
        const int2 r3 = sorted[j + 3];
        const u16x4 g0 = *(const u16x4*)(gb + (size_t)r0.y * WCOLS);
        const u16x4 g1 = *(const u16x4*)(gb + (size_t)r1.y * WCOLS);
        const u16x4 g2 = *(const u16x4*)(gb + (size_t)r2.y * WCOLS);
        const u16x4 g3 = *(const u16x4*)(gb + (size_t)r3.y * WCOLS);
        const float q0 = fmaf(qsign, __int_as_float(r0.x), qbase);
        const float q1 = fmaf(qsign, __int_as_float(r1.x), qbase);
        const float q2 = fmaf(qsign, __int_as_float(r2.x), qbase);
        const float q3 = fmaf(qsign, __int_as_float(r3.x), qbase);
        a0.x = fmaf(q0, bf16_bits_to_f32(g0[0]), a0.x);
        a0.y = fmaf(q0, bf16_bits_to_f32(g0[1]), a0.y);
        a0.z = fmaf(q0, bf16_bits_to_f32(g0[2]), a0.z);
        a0.w = fmaf(q0, bf16_bits_to_f32(g0[3]), a0.w);
        a1.x = fmaf(q1, bf16_bits_to_f32(g1[0]), a1.x);
        a1.y = fmaf(q1, bf16_bits_to_f32(g1[1]), a1.y);
        a1.z = fmaf(q1, bf16_bits_to_f32(g1[2]), a1.z);
        a1.w = fmaf(q1, bf16_bits_to_f32(g1[3]), a1.w);
        a2.x = fmaf(q2, bf16_bits_to_f32(g2[0]), a2.x);
        a2.y = fmaf(q2, bf16_bits_to_f32(g2[1]), a2.y);
        a2.z = fmaf(q2, bf16_bits_to_f32(g2[2]), a2.z);
        a2.w = fmaf(q2, bf16_bits_to_f32(g2[3]), a2.w);
        a3.x = fmaf(q3, bf16_bits_to_f32(g3[0]), a3.x);
        a3.y = fmaf(q3, bf16_bits_to_f32(g3[1]), a3.y);
        a3.z = fmaf(q3, bf16_bits_to_f32(g3[2]), a3.z);
        a3.w = fmaf(q3, bf16_bits_to_f32(g3[3]), a3.w);
    }
    for (; j < end; ++j) {
        const int2 r = sorted[j];
        const u16x4 g = *(const u16x4*)(gb + (size_t)r.y * WCOLS);
        const float q = fmaf(qsign, __int_as_float(r.x), qbase);
        a0.x = fmaf(q, bf16_bits_to_f32(g[0]), a0.x);
        a0.y = fmaf(q, bf16_bits_to_f32(g[1]), a0.y);
        a0.z = fmaf(q, bf16_bits_to_f32(g[2]), a0.z);
        a0.w = fmaf(q, bf16_bits_to_f32(g[3]), a0.w);
    }
    float4 t;
    t.x = (a0.x + a1.x) + (a2.x + a3.x);
    t.y = (a0.y + a1.y) + (a2.y + a3.y);
    t.z = (a0.z + a1.z) + (a2.z + a3.z);
    t.w = (a0.w + a1.w) + (a2.w + a3.w);
    // fold head1 partial into head0 lanes
    t.x += __shfl_xor(t.x, 32, 64);
    t.y += __shfl_xor(t.y, 32, 64);
    t.z += __shfl_xor(t.z, 32, 64);
    t.w += __shfl_xor(t.w, 32, 64);
    if (half == 0) {
        const float inv = 1.0f / (float)deg;
        const float4 bv = *(const float4*)(bias + 4 * l5);
        const float4 xv = *(const float4*)(x + (size_t)n * F_IN + 4 * l5);
        float4 r;
        r.x = xv.x + fmaxf(fmaf(t.x, inv, bv.x), 0.f);
        r.y = xv.y + fmaxf(fmaf(t.y, inv, bv.y), 0.f);
        r.z = xv.z + fmaxf(fmaf(t.z, inv, bv.z), 0.f);
        r.w = xv.w + fmaxf(fmaf(t.w, inv, bv.w), 0.f);
        *(float4*)(out + (size_t)n * F_OUT + 4 * l5) = r;
    }
}

// ---------------------------------------------------------------------------
extern "C" void kernel_launch(void* const* d_in, const int* in_sizes, int n_in,
                              void* d_out, int out_size, void* d_ws, size_t ws_size,
                              hipStream_t stream) {
    const float* x    = (const float*)d_in[0];
    const int*   ei   = (const int*)  d_in[1];   // [2, N_EDGES] flat
    const float* u    = (const float*)d_in[2];
    const float* c    = (const float*)d_in[3];
    const float* w    = (const float*)d_in[4];
    const float* bias = (const float*)d_in[5];
    float* out = (float*)d_out;

    // workspace layout (16B-aligned segments):
    //   xwb      [N*256 bf16]  25,600,000 B
    //   s        [N   f32x2]      400,000 B
    //   hist     [N   i32]        200,000 B
    //   cursor   [N   i32]        200,000 B
    //   partials [64  i32]            256 B
    //   wT       [256*128 bf16]    65,536 B
    //   sorted   [E_TOT int2]   6,800,000 B
    char* p = (char*)d_ws;
    unsigned short* xwb = (unsigned short*)p;  p += (size_t)N_NODES * WCOLS * sizeof(unsigned short);
    float2* s      = (float2*)p;               p += (size_t)N_NODES * sizeof(float2);
    int*    hist   = (int*)p;                  p += (size_t)N_NODES * sizeof(int);
    int*    cursor = (int*)p;                  p += (size_t)N_NODES * sizeof(int);
    int*    partials = (int*)p;                p += 256;
    unsigned short* wT = (unsigned short*)p;   p += (size_t)WCOLS * F_IN * sizeof(unsigned short);
    int2*   sorted = (int2*)p;

    // 0) wT = bf16(w^T)
    wt_kernel<<<(WCOLS * F_IN) / 256, 256, 0, stream>>>(w, wT);

    // 1) xwb = bf16(x @ w)  (MFMA)
    proj_kernel<<<N_NODES / 16, 256, 0, stream>>>(x, wT, xwb);

    // 2) s = x @ u
    sproj_kernel<<<(N_NODES + 3) / 4, 256, 0, stream>>>(x, u, s);

    // 3) dst histogram: init to 1 (self), add real in-edges
    hist_init<<<(N_NODES + 255) / 256, 256, 0, stream>>>(hist);
    hist_kernel<<<(N_EDGES + 255) / 256, 256, 0, stream>>>(ei, hist);

    // 4) exclusive scan -> cursor (3-phase), +1 shift reserving self slots
    scan_part<<<N_SCAN_BLOCKS, SCAN_BLOCK, 0, stream>>>(hist, cursor, partials);
    scan_mid<<<1, 64, 0, stream>>>(partials);
    scan_add<<<N_SCAN_BLOCKS, SCAN_BLOCK, 0, stream>>>(cursor, partials);

    // 4d) deterministic self-loop records
    self_place<<<(N_NODES + 255) / 256, 256, 0, stream>>>(c, cursor, sorted);

    // 5) attention + scatter into dst-sorted order (real edges)
    scatter_kernel<<<(N_EDGES + 255) / 256, 256, 0, stream>>>(ei, s, c, cursor, sorted);

    // 6) aggregate + finalize
    agg_kernel<<<(N_NODES + 3) / 4, 256, 0, stream>>>(x, bias, xwb, sorted, hist, cursor, out);
}